// Round 4
// baseline (329.279 us; speedup 1.0000x reference)
//
#include <hip/hip_runtime.h>
#include <math.h>

// SigmaMoE R11: T=4096, H=1024, I=512, E=16, top-2, shared IS=1024.
//  - R10 post-mortem: occupancy rose (34%) but MfmaUtil stuck at 21% ->
//    not a scheduling problem. LDS traffic audit: 48KB/chunk/block =
//    ~32 TB/s = ~71% of achievable b128 ceiling -> LDS-BW-bound.
//  - Fix: B (N-major weights) fragments loaded DIRECT global->reg (L2-hit,
//    each frag 16 contiguous bytes); only A staged via global_load_lds.
//    LDS traffic halved (24KB/chunk), LDS block 16KB. Unroll-2 pipeline,
//    vmcnt(6) counted waits, register-double-buffered B (static indices).
//  - Reverted R10's atomicAdd epilogue (cost ~20us): back to y0/y1+k_final.
#define H_DIM 1024
#define I_DIM 512
#define E_NUM 16
#define T_TOK 4096
#define IS_DIM 1024
#define CSTR 32       // cnt stride in ints (128B = own cache line per expert)

// k_prep block ranges
#define P_RT   1024               // router blocks (4 tokens each)
#define P_WU   (P_RT + 2048)      // wg transpose [P_RT, P_WU)
#define P_SG   (P_WU + 2048)      // wu transpose
#define P_SU   (P_SG + 256)       // sg transpose
#define P_END  (P_SU + 256)       // su transpose

// k_gateup: GEMM blocks FIRST, transpose blocks at tail.
#define G_GEMM 1152               // 512 shared + <=640 routed
#define G_TR   2304               // wd (2048) + sd (256)
#define G_END  (G_GEMM + G_TR)

#define D_GRID 896                // 256 shared + <=640 routed

typedef unsigned short u16;
typedef __attribute__((ext_vector_type(8))) short short8;   // 8 x bf16 (16B)
typedef __attribute__((ext_vector_type(4))) float floatx4;  // 16x16 acc

#define VM6   asm volatile("s_waitcnt vmcnt(6)" ::: "memory")
#define VM0   asm volatile("s_waitcnt vmcnt(0)" ::: "memory")
#define LGKM0 asm volatile("s_waitcnt lgkmcnt(0)" ::: "memory")
#define BAR   __builtin_amdgcn_s_barrier()

__device__ __forceinline__ float bf2f(u16 u) {
    union { unsigned int u; float f; } c; c.u = ((unsigned int)u) << 16; return c.f;
}
__device__ __forceinline__ u16 f2bf(float f) {
    union { float f; unsigned int u; } c; c.f = f;
    unsigned int r = (c.u + 0x7fffu + ((c.u >> 16) & 1u)) >> 16;
    return (u16)r;
}
// async global->LDS, 16B/lane; LDS dest = wave-uniform base + lane*16.
__device__ __forceinline__ void gld16(const u16* g, u16* l) {
    __builtin_amdgcn_global_load_lds(
        (const __attribute__((address_space(1))) unsigned int*)g,
        (__attribute__((address_space(3))) unsigned int*)l, 16, 0, 0);
}

// ---------------------------------------------------------------------------
// 64x64 convert+transpose tile: f32 K-major -> bf16 N-major. tile = 64*65 u16.
// ---------------------------------------------------------------------------
__device__ __forceinline__ void tr64(const float* src, u16* dst, int R, int C,
                                     int local, u16* tile)
{
    int tpm = (R >> 6) * (C >> 6);
    int mat = local / tpm;
    int tl_ = local - mat * tpm;
    int tcn = C >> 6;
    int tr = tl_ / tcn, tc = tl_ - tr * tcn;
    src += (size_t)mat * R * C;
    dst += (size_t)mat * R * C;
    int t = threadIdx.x;
    int r0 = t >> 2, c0 = (t & 3) << 4;
    const float* sp = src + (size_t)(tr * 64 + r0) * C + tc * 64 + c0;
    #pragma unroll
    for (int j = 0; j < 16; j += 4) {
        float4 v = *(const float4*)(sp + j);
        tile[r0 * 65 + c0 + j + 0] = f2bf(v.x);
        tile[r0 * 65 + c0 + j + 1] = f2bf(v.y);
        tile[r0 * 65 + c0 + j + 2] = f2bf(v.z);
        tile[r0 * 65 + c0 + j + 3] = f2bf(v.w);
    }
    __syncthreads();
    int cW = t >> 2, rW = (t & 3) << 4;
    u16 tmp[16];
    #pragma unroll
    for (int j = 0; j < 16; ++j) tmp[j] = tile[(rW + j) * 65 + cW];
    u16* dp = dst + (size_t)(tc * 64 + cW) * R + tr * 64 + rW;
    *(uint4*)(dp)     = *(const uint4*)(tmp);
    *(uint4*)(dp + 8) = *(const uint4*)(tmp + 8);
}

// ---------------------------------------------------------------------------
// Map a routed block index to (expert, m-tile, sub-tile, act row base).
// ---------------------------------------------------------------------------
__device__ __forceinline__ int derive_routed(int gi, const int* cnt,
                                             int& e, int& mt, int& sub, int& abase)
{
    int off = 0, b = 0;
    #pragma unroll
    for (int ee = 0; ee < E_NUM; ++ee) {
        int mts = (cnt[ee * CSTR] + 127) >> 7;
        int span = mts << 3;
        if (gi < off + span) {
            int local = gi - off;
            e = ee; mt = local >> 3; sub = local & 7; abase = b;
            return 1;
        }
        off += span; b += mts << 7;
    }
    return 0;
}

// ---------------------------------------------------------------------------
// k_prep: router (+ xb emission) and gate/up + shared gate/up transposes.
// ---------------------------------------------------------------------------
__global__ __launch_bounds__(256, 4)
void k_prep(const float* x, const float* rw,
            const float* wg, const float* wu, const float* sg, const float* su,
            u16* wgt, u16* wut, u16* sgt, u16* sut,
            u16* xb, float* topkw, int* elist, int* cnt)
{
    __shared__ u16 tile[64 * 65];
    int bi = blockIdx.x;
    if (bi >= P_RT) {
        if (bi < P_WU)      tr64(wg, wgt, 1024, 512,  bi - P_RT, tile);
        else if (bi < P_SG) tr64(wu, wut, 1024, 512,  bi - P_WU, tile);
        else if (bi < P_SU) tr64(sg, sgt, 1024, 1024, bi - P_SG, tile);
        else                tr64(su, sut, 1024, 1024, bi - P_SU, tile);
        return;
    }
    // ---- router + x->bf16 (4 tokens per block, 1 wave each) ----
    int lane = threadIdx.x & 63;
    int wv = threadIdx.x >> 6;
    int t = bi * 4 + wv;
    const float* xr = x + (size_t)t * H_DIM;
    float xv[16];
    #pragma unroll
    for (int j = 0; j < 16; ++j) xv[j] = xr[j * 64 + lane];
    u16* xrow = xb + (size_t)t * H_DIM;
    #pragma unroll
    for (int j = 0; j < 16; ++j) xrow[j * 64 + lane] = f2bf(xv[j]);
    float sc[E_NUM];
    #pragma unroll
    for (int e = 0; e < E_NUM; ++e) sc[e] = 0.f;
    #pragma unroll
    for (int e = 0; e < E_NUM; ++e) {
        const float* rr = rw + e * H_DIM;
        #pragma unroll
        for (int j = 0; j < 16; ++j) sc[e] += xv[j] * rr[j * 64 + lane];
    }
    #pragma unroll
    for (int off = 32; off > 0; off >>= 1) {
        float tmp[E_NUM];
        #pragma unroll
        for (int e = 0; e < E_NUM; ++e) tmp[e] = __shfl_xor(sc[e], off, 64);
        #pragma unroll
        for (int e = 0; e < E_NUM; ++e) sc[e] += tmp[e];
    }
    if (lane == 0) {
        float b1 = -1e30f, b2 = -1e30f; int i1 = 0, i2 = 0;
        #pragma unroll
        for (int e = 0; e < E_NUM; ++e) {
            if (sc[e] > b1) { b2 = b1; i2 = i1; b1 = sc[e]; i1 = e; }
            else if (sc[e] > b2) { b2 = sc[e]; i2 = e; }
        }
        float w1 = 1.f / (1.f + __expf(b2 - b1));
        float w2 = 1.f - w1;
        topkw[t * 2]     = w1;
        topkw[t * 2 + 1] = w2;
        int p1 = atomicAdd(&cnt[i1 * CSTR], 1); elist[i1 * T_TOK + p1] = (t << 1);
        int p2 = atomicAdd(&cnt[i2 * CSTR], 1); elist[i2 * T_TOK + p2] = (t << 1) | 1;
    }
}

// ---------------------------------------------------------------------------
// Fused gate/up GEMM: A via LDS (16KB dbuf), B direct global->reg (L2-hit).
// Block = 128 rows x (64 g + 64 u), BK=32/chunk, unroll-2, vmcnt(6).
// wd/sd transposes ride at the grid TAIL.
// ---------------------------------------------------------------------------
__global__ __launch_bounds__(256, 3)
void k_gateup(const u16* xb, const u16* wgt, const u16* wut,
              const u16* sgt, const u16* sut,
              const float* wd, const float* sd, u16* wdt, u16* sdt,
              const int* elist, const int* cnt,
              u16* act, u16* sact)
{
    __shared__ u16 smem[8192];   // 16 KB: 2 x 4096-u16 A buffers
    int bi = blockIdx.x;
    if (bi >= G_GEMM) {
        int tb = bi - G_GEMM;
        if (tb < 2048) tr64(wd, wdt, 512, 1024, tb, smem);
        else           tr64(sd, sdt, 1024, 1024, tb - 2048, smem);
        return;
    }
    int kind, e = 0, mt, cb, abase = 0;
    if (bi < 512) { kind = 1; mt = bi >> 4; cb = bi & 15; }
    else {
        kind = 0;
        if (!derive_routed(bi - 512, cnt, e, mt, cb, abase)) return;
    }

    int tid = threadIdx.x, lane = tid & 63, w = tid >> 6;
    int srow = lane >> 2, scp = lane & 3;

    const u16* gb = kind ? sgt : (wgt + (size_t)e * I_DIM * H_DIM);
    const u16* ub = kind ? sut : (wut + (size_t)e * I_DIM * H_DIM);
    int c = cnt[e * CSTR];

    // A staging: per wave 2 gld16 rows-groups
    const u16 *gA0, *gA1;
    int oA0, oA1;
    {
        int row0 = (w * 2) * 16 + srow;           // 0..127
        int row1 = (w * 2 + 1) * 16 + srow;
        int gc0 = scp ^ ((row0 >> 1) & 3);
        int gc1 = scp ^ ((row1 >> 1) & 3);
        int tok0, tok1;
        if (kind) { tok0 = mt * 128 + row0; tok1 = mt * 128 + row1; }
        else {
            int p0 = mt * 128 + row0; int pc0 = p0 < c ? p0 : c - 1;
            int p1 = mt * 128 + row1; int pc1 = p1 < c ? p1 : c - 1;
            tok0 = elist[e * T_TOK + pc0] >> 1;
            tok1 = elist[e * T_TOK + pc1] >> 1;
        }
        gA0 = xb + (size_t)tok0 * H_DIM + gc0 * 8;
        gA1 = xb + (size_t)tok1 * H_DIM + gc1 * 8;
        oA0 = (w * 2) * 512;
        oA1 = (w * 2 + 1) * 512;
    }

    int wr = w >> 1, wc = w & 1;
    int quad = lane >> 4, l15 = lane & 15;
    int fA[4];
    #pragma unroll
    for (int i = 0; i < 4; ++i) {
        int r = wr * 64 + i * 16 + l15;
        fA[i] = r * 32 + (quad ^ ((r >> 1) & 3)) * 8;
    }
    // B fragment global bases (k=0): lane reads B[n][quad*8 .. +8]
    const u16* bG0 = gb + (size_t)(cb * 64 + wc * 32 + 0  + l15) * H_DIM + quad * 8;
    const u16* bG1 = gb + (size_t)(cb * 64 + wc * 32 + 16 + l15) * H_DIM + quad * 8;
    const u16* bU0 = ub + (size_t)(cb * 64 + wc * 32 + 0  + l15) * H_DIM + quad * 8;
    const u16* bU1 = ub + (size_t)(cb * 64 + wc * 32 + 16 + l15) * H_DIM + quad * 8;

    floatx4 accg[4][2], accu[4][2];
    #pragma unroll
    for (int i = 0; i < 4; ++i)
        #pragma unroll
        for (int j = 0; j < 2; ++j)
            #pragma unroll
            for (int r = 0; r < 4; ++r) { accg[i][j][r] = 0.f; accu[i][j][r] = 0.f; }

    short8 gS[2][2], uS[2][2];    // [set][frag] — indices always literal

#define STAGEA(bsel, kk) { \
    u16* sb = smem + (bsel) * 4096; \
    gld16(gA0 + (kk), sb + oA0); \
    gld16(gA1 + (kk), sb + oA1); }

#define LOADB(set, kk) { \
    gS[set][0] = *(const short8*)(bG0 + (kk)); \
    gS[set][1] = *(const short8*)(bG1 + (kk)); \
    uS[set][0] = *(const short8*)(bU0 + (kk)); \
    uS[set][1] = *(const short8*)(bU1 + (kk)); }

#define COMPUTE_GU(bsel, set) { \
    const u16* cb_ = smem + (bsel) * 4096; \
    short8 a_[4]; \
    _Pragma("unroll") \
    for (int i_ = 0; i_ < 4; ++i_) a_[i_] = *(const short8*)(cb_ + fA[i_]); \
    _Pragma("unroll") \
    for (int i_ = 0; i_ < 4; ++i_) { \
        accg[i_][0] = __builtin_amdgcn_mfma_f32_16x16x32_bf16(a_[i_], gS[set][0], accg[i_][0], 0, 0, 0); \
        accg[i_][1] = __builtin_amdgcn_mfma_f32_16x16x32_bf16(a_[i_], gS[set][1], accg[i_][1], 0, 0, 0); \
        accu[i_][0] = __builtin_amdgcn_mfma_f32_16x16x32_bf16(a_[i_], uS[set][0], accu[i_][0], 0, 0, 0); \
        accu[i_][1] = __builtin_amdgcn_mfma_f32_16x16x32_bf16(a_[i_], uS[set][1], accu[i_][1], 0, 0, 0); \
    } }

    STAGEA(0, 0);
    LOADB(0, 0);
    const int nt = H_DIM / 32;   // 32 chunks, even
    for (int t = 0; t < nt; t += 2) {
        { int k1 = (t + 1) * 32;
          STAGEA(1, k1); LOADB(1, k1); VM6; }
        BAR;
        COMPUTE_GU(0, 0);
        LGKM0; BAR;
        if (t + 2 < nt) {
            int k2 = (t + 2) * 32;
            STAGEA(0, k2); LOADB(0, k2); VM6;
        } else VM0;
        BAR;
        COMPUTE_GU(1, 1);
        LGKM0; BAR;
    }
#undef STAGEA
#undef LOADB
#undef COMPUTE_GU

    u16* obase = kind ? (sact + (size_t)(mt * 128) * IS_DIM)
                      : (act + (size_t)(abase + mt * 128) * I_DIM);
    int old = kind ? IS_DIM : I_DIM;
    #pragma unroll
    for (int i = 0; i < 4; ++i)
        #pragma unroll
        for (int j = 0; j < 2; ++j)
            #pragma unroll
            for (int r = 0; r < 4; ++r) {
                int row = wr * 64 + i * 16 + quad * 4 + r;
                int col = cb * 64 + wc * 32 + j * 16 + l15;
                float gg = accg[i][j][r], uu = accu[i][j][r];
                float aa = gg / (1.f + __expf(-gg)) * uu;   // silu(g)*u
                obase[(size_t)row * old + col] = f2bf(aa);
            }
}

// ---------------------------------------------------------------------------
// Fused down GEMM, 128x128 per block: A via LDS (16KB dbuf), B direct
// global->reg. Routed K=512 -> y0/y1 scatter; shared K=1024 -> f32 out.
// ---------------------------------------------------------------------------
__global__ __launch_bounds__(256, 3)
void k_down(const u16* act, const u16* sact, const u16* wdt, const u16* sdt,
            const int* elist, const int* cnt, const float* topkw,
            u16* y0, u16* y1, float* out)
{
    int bi = blockIdx.x;
    int kind, e = 0, mt, nb, abase = 0;
    if (bi < 256) { kind = 1; mt = bi >> 3; nb = bi & 7; }     // 32 mts x 8 nbs
    else {
        kind = 0;
        if (!derive_routed(bi - 256, cnt, e, mt, nb, abase)) return;
    }

    __shared__ u16 smem[8192];   // 16 KB: 2 x 4096-u16 A buffers
    int tid = threadIdx.x, lane = tid & 63, w = tid >> 6;
    int srow = lane >> 2, scp = lane & 3;

    int K = kind ? IS_DIM : I_DIM;
    const u16* ab = kind ? (sact + (size_t)(mt * 128) * IS_DIM)
                         : (act + (size_t)(abase + mt * 128) * I_DIM);
    const u16* bb = kind ? (sdt + (size_t)(nb * 128) * IS_DIM)
                         : (wdt + ((size_t)e * H_DIM + nb * 128) * I_DIM);
    int c = cnt[e * CSTR];

    const u16 *gA0, *gA1;
    int oA0, oA1;
    {
        int row0 = (w * 2) * 16 + srow;
        int row1 = (w * 2 + 1) * 16 + srow;
        int gc0 = scp ^ ((row0 >> 1) & 3);
        int gc1 = scp ^ ((row1 >> 1) & 3);
        gA0 = ab + (size_t)row0 * K + gc0 * 8;
        gA1 = ab + (size_t)row1 * K + gc1 * 8;
        oA0 = (w * 2) * 512;
        oA1 = (w * 2 + 1) * 512;
    }

    int wr = w >> 1, wc = w & 1;
    int quad = lane >> 4, l15 = lane & 15;
    int fA[4];
    #pragma unroll
    for (int i = 0; i < 4; ++i) {
        int r = wr * 64 + i * 16 + l15;
        fA[i] = r * 32 + (quad ^ ((r >> 1) & 3)) * 8;
    }
    const u16* bB0 = bb + (size_t)(nb * 0 + wc * 64 + 0  + l15) * K + quad * 8;
    const u16* bB1 = bb + (size_t)(wc * 64 + 16 + l15) * K + quad * 8;
    const u16* bB2 = bb + (size_t)(wc * 64 + 32 + l15) * K + quad * 8;
    const u16* bB3 = bb + (size_t)(wc * 64 + 48 + l15) * K + quad * 8;

    floatx4 acc[4][4];
    #pragma unroll
    for (int i = 0; i < 4; ++i)
        #pragma unroll
        for (int j = 0; j < 4; ++j)
            #pragma unroll
            for (int r = 0; r < 4; ++r) acc[i][j][r] = 0.f;

    short8 bS[2][4];

#define STAGEA(bsel, kk) { \
    u16* sb = smem + (bsel) * 4096; \
    gld16(gA0 + (kk), sb + oA0); \
    gld16(gA1 + (kk), sb + oA1); }

#define LOADB(set, kk) { \
    bS[set][0] = *(const short8*)(bB0 + (kk)); \
    bS[set][1] = *(const short8*)(bB1 + (kk)); \
    bS[set][2] = *(const short8*)(bB2 + (kk)); \
    bS[set][3] = *(const short8*)(bB3 + (kk)); }

#define COMPUTE_DN(bsel, set) { \
    const u16* cb_ = smem + (bsel) * 4096; \
    short8 a_[4]; \
    _Pragma("unroll") \
    for (int i_ = 0; i_ < 4; ++i_) a_[i_] = *(const short8*)(cb_ + fA[i_]); \
    _Pragma("unroll") \
    for (int i_ = 0; i_ < 4; ++i_) { \
        acc[i_][0] = __builtin_amdgcn_mfma_f32_16x16x32_bf16(a_[i_], bS[set][0], acc[i_][0], 0, 0, 0); \
        acc[i_][1] = __builtin_amdgcn_mfma_f32_16x16x32_bf16(a_[i_], bS[set][1], acc[i_][1], 0, 0, 0); \
        acc[i_][2] = __builtin_amdgcn_mfma_f32_16x16x32_bf16(a_[i_], bS[set][2], acc[i_][2], 0, 0, 0); \
        acc[i_][3] = __builtin_amdgcn_mfma_f32_16x16x32_bf16(a_[i_], bS[set][3], acc[i_][3], 0, 0, 0); \
    } }

    const int nt = K >> 5;       // 16 or 32, even
    STAGEA(0, 0);
    LOADB(0, 0);
    for (int t = 0; t < nt; t += 2) {
        { int k1 = (t + 1) * 32;
          STAGEA(1, k1); LOADB(1, k1); VM6; }
        BAR;
        COMPUTE_DN(0, 0);
        LGKM0; BAR;
        if (t + 2 < nt) {
            int k2 = (t + 2) * 32;
            STAGEA(0, k2); LOADB(0, k2); VM6;
        } else VM0;
        BAR;
        COMPUTE_DN(1, 1);
        LGKM0; BAR;
    }
#undef STAGEA
#undef LOADB
#undef COMPUTE_DN

    if (kind) {
        #pragma unroll
        for (int i = 0; i < 4; ++i)
            #pragma unroll
            for (int j = 0; j < 4; ++j)
                #pragma unroll
                for (int r = 0; r < 4; ++r) {
                    int row = mt * 128 + wr * 64 + i * 16 + quad * 4 + r;
                    int col = nb * 128 + wc * 64 + j * 16 + l15;
                    out[(size_t)row * H_DIM + col] = acc[i][j][r];
                }
    } else {
        #pragma unroll
        for (int i = 0; i < 4; ++i)
            #pragma unroll
            for (int r = 0; r < 4; ++r) {
                int row = wr * 64 + i * 16 + quad * 4 + r;
                int p = mt * 128 + row;
                if (p < c) {
                    int ent = elist[e * T_TOK + p];
                    int t = ent >> 1, sl = ent & 1;
                    float wt = topkw[t * 2 + sl];
                    u16* yb = sl ? y1 : y0;
                    #pragma unroll
                    for (int j = 0; j < 4; ++j) {
                        int col = nb * 128 + wc * 64 + j * 16 + l15;
                        yb[(size_t)t * H_DIM + col] = f2bf(wt * acc[i][j][r]);
                    }
                }
            }
    }
}

// Final combine: out += y0 + y1 (out already holds shared-expert result).
__global__ __launch_bounds__(256)
void k_final(float* out, const u16* y0, const u16* y1)
{
    int i = blockIdx.x * 256 + threadIdx.x;
    float4 o = ((const float4*)out)[i];
    uint2 a = ((const uint2*)y0)[i];
    uint2 b = ((const uint2*)y1)[i];
    const u16* pa = (const u16*)&a;
    const u16* pb = (const u16*)&b;
    o.x += bf2f(pa[0]) + bf2f(pb[0]);
    o.y += bf2f(pa[1]) + bf2f(pb[1]);
    o.z += bf2f(pa[2]) + bf2f(pb[2]);
    o.w += bf2f(pa[3]) + bf2f(pb[3]);
    ((float4*)out)[i] = o;
}

// ---------------------------------------------------------------------------
extern "C" void kernel_launch(void* const* d_in, const int* in_sizes, int n_in,
                              void* d_out, int out_size, void* d_ws, size_t ws_size,
                              hipStream_t stream)
{
    const float* x  = (const float*)d_in[0];
    const float* rw = (const float*)d_in[1];
    const float* wg = (const float*)d_in[2];
    const float* wu = (const float*)d_in[3];
    const float* wd = (const float*)d_in[4];
    const float* sg = (const float*)d_in[5];
    const float* su = (const float*)d_in[6];
    const float* sd = (const float*)d_in[7];
    float* out = (float*)d_out;

    char* ws = (char*)d_ws;
    const size_t MB = 1024ull * 1024ull;
    u16* wgt  = (u16*)(ws);            // [E][I][H] bf16  16 MB
    u16* wut  = (u16*)(ws + 16 * MB);  // [E][I][H]       16 MB
    u16* wdt  = (u16*)(ws + 32 * MB);  // [E][H][I]       16 MB
    u16* sgt  = (u16*)(ws + 48 * MB);  // [IS][H]          2 MB
    u16* sut  = (u16*)(ws + 50 * MB);  // [IS][H]          2 MB
    u16* sdt  = (u16*)(ws + 52 * MB);  // [H][IS]          2 MB
    u16* xb   = (u16*)(ws + 54 * MB);  // [T][H] bf16      8 MB
    u16* act  = (u16*)(ws + 62 * MB);  // [<=10240][I]    10 MB (128-padded rows)
    u16* sact = (u16*)(ws + 72 * MB);  // [T][IS]          8 MB
    u16* y0   = (u16*)(ws + 80 * MB);  // [T][H] slot0     8 MB
    u16* y1   = (u16*)(ws + 88 * MB);  // [T][H] slot1     8 MB
    float* topkw  = (float*)(ws + 96 * MB);            // [T][2]
    int* elist    = (int*)(ws + 96 * MB + 64 * 1024);  // [E][T]
    int* cnt      = (int*)(ws + 97 * MB);              // [E] stride CSTR

    hipMemsetAsync(cnt, 0, E_NUM * CSTR * sizeof(int), stream);
    k_prep<<<P_END, 256, 0, stream>>>(x, rw, wg, wu, sg, su,
                                      wgt, wut, sgt, sut,
                                      xb, topkw, elist, cnt);
    k_gateup<<<G_END, 256, 0, stream>>>(xb, wgt, wut, sgt, sut,
                                        wd, sd, wdt, sdt,
                                        elist, cnt, act, sact);
    k_down<<<D_GRID, 256, 0, stream>>>(act, sact, wdt, sdt,
                                       elist, cnt, topkw, y0, y1, out);
    k_final<<<T_TOK * H_DIM / 4 / 256, 256, 0, stream>>>(out, y0, y1);
}

// Round 5
// 279.417 us; speedup vs baseline: 1.1784x; 1.1784x over previous
//
#include <hip/hip_runtime.h>
#include <math.h>

// SigmaMoE R12: T=4096, H=1024, I=512, E=16, top-2, shared IS=1024.
// 8-phase 256-tile GEMM core (m201 template port) for k_gateup and k_down:
//   BM=256, BN=256 (gateup: 128 g + 128 u cols), BK=64, 8 waves (2Mx4N),
//   128KB LDS double-buffer, per-wave output 128x64 (raises MFMA/LDS-byte:
//   R4 analysis showed the 128-tile was LDS-BW-capped at ~40% MfmaUtil).
//   Per phase: stage 1 half-tile -> ds_read frags -> counted vmcnt -> bar ->
//   lgkm+sched_barrier -> setprio(1) 16 MFMA setprio(0) -> bar.
//   Half-tile ledger (order Ah0,Ah1,Bh0,Bh1): stage h=q+5 at phase q;
//   steady vmcnt {4,6,6,4}; t=nt-2 p3 -> 2; t=nt-1 -> 0. Never drain-0 mid-loop.
// wd/sd transposes: 128x128 tiles at gateup grid tail. Revert R11 B-direct.
#define H_DIM 1024
#define I_DIM 512
#define E_NUM 16
#define T_TOK 4096
#define IS_DIM 1024
#define CSTR 32

// k_prep ranges: router + gate/up + shared gate/up transposes
#define P_RT   1024
#define P_WU   (P_RT + 2048)
#define P_SG   (P_WU + 2048)
#define P_SU   (P_SG + 256)
#define P_END  (P_SU + 256)

// k_gateup: 128 shared + <=224 routed GEMM blocks, then 576 tr128 blocks
#define G_GEMM 352
#define G_TR   576
#define G_END  (G_GEMM + G_TR)

#define D_GRID 288               // 64 shared + <=224 routed

typedef unsigned short u16;
typedef __attribute__((ext_vector_type(8))) short short8;
typedef __attribute__((ext_vector_type(4))) float floatx4;

#define VM0   asm volatile("s_waitcnt vmcnt(0)" ::: "memory")
#define VM2   asm volatile("s_waitcnt vmcnt(2)" ::: "memory")
#define VM4   asm volatile("s_waitcnt vmcnt(4)" ::: "memory")
#define VM6   asm volatile("s_waitcnt vmcnt(6)" ::: "memory")
#define LGKM0 asm volatile("s_waitcnt lgkmcnt(0)" ::: "memory")
#define BAR   __builtin_amdgcn_s_barrier()
#define SCHB  __builtin_amdgcn_sched_barrier(0)

__device__ __forceinline__ float bf2f(u16 u) {
    union { unsigned int u; float f; } c; c.u = ((unsigned int)u) << 16; return c.f;
}
__device__ __forceinline__ u16 f2bf(float f) {
    union { float f; unsigned int u; } c; c.f = f;
    unsigned int r = (c.u + 0x7fffu + ((c.u >> 16) & 1u)) >> 16;
    return (u16)r;
}
__device__ __forceinline__ void gld16(const u16* g, u16* l) {
    __builtin_amdgcn_global_load_lds(
        (const __attribute__((address_space(1))) unsigned int*)g,
        (__attribute__((address_space(3))) unsigned int*)l, 16, 0, 0);
}

// ---------------------------------------------------------------------------
// 64x64 f32->bf16 transpose tile (256 threads) for k_prep.
// ---------------------------------------------------------------------------
__device__ __forceinline__ void tr64(const float* src, u16* dst, int R, int C,
                                     int local, u16* tile)
{
    int tpm = (R >> 6) * (C >> 6);
    int mat = local / tpm;
    int tl_ = local - mat * tpm;
    int tcn = C >> 6;
    int tr = tl_ / tcn, tc = tl_ - tr * tcn;
    src += (size_t)mat * R * C;
    dst += (size_t)mat * R * C;
    int t = threadIdx.x;
    int r0 = t >> 2, c0 = (t & 3) << 4;
    const float* sp = src + (size_t)(tr * 64 + r0) * C + tc * 64 + c0;
    #pragma unroll
    for (int j = 0; j < 16; j += 4) {
        float4 v = *(const float4*)(sp + j);
        tile[r0 * 65 + c0 + j + 0] = f2bf(v.x);
        tile[r0 * 65 + c0 + j + 1] = f2bf(v.y);
        tile[r0 * 65 + c0 + j + 2] = f2bf(v.z);
        tile[r0 * 65 + c0 + j + 3] = f2bf(v.w);
    }
    __syncthreads();
    int cW = t >> 2, rW = (t & 3) << 4;
    u16 tmp[16];
    #pragma unroll
    for (int j = 0; j < 16; ++j) tmp[j] = tile[(rW + j) * 65 + cW];
    u16* dp = dst + (size_t)(tc * 64 + cW) * R + tr * 64 + rW;
    *(uint4*)(dp)     = *(const uint4*)(tmp);
    *(uint4*)(dp + 8) = *(const uint4*)(tmp + 8);
}

// ---------------------------------------------------------------------------
// 128x128 f32->bf16 transpose tile (512 threads) for k_gateup tail.
// ---------------------------------------------------------------------------
__device__ __forceinline__ void tr128(const float* src, u16* dst, int R, int C,
                                      int local, u16* tile /* >=128*129 u16 */)
{
    int tpm = (R >> 7) * (C >> 7);
    int mat = local / tpm;
    int tl_ = local - mat * tpm;
    int tcn = C >> 7;
    int tr = tl_ / tcn, tc = tl_ - tr * tcn;
    src += (size_t)mat * R * C;
    dst += (size_t)mat * R * C;
    int t = threadIdx.x;                    // 0..511
    int r0 = t >> 2, c0 = (t & 3) << 5;     // 128 rows x 32 cols each
    const float* sp = src + (size_t)(tr * 128 + r0) * C + tc * 128 + c0;
    #pragma unroll
    for (int j = 0; j < 32; j += 4) {
        float4 v = *(const float4*)(sp + j);
        tile[r0 * 129 + c0 + j + 0] = f2bf(v.x);
        tile[r0 * 129 + c0 + j + 1] = f2bf(v.y);
        tile[r0 * 129 + c0 + j + 2] = f2bf(v.z);
        tile[r0 * 129 + c0 + j + 3] = f2bf(v.w);
    }
    __syncthreads();
    int cW = t >> 2, rW = (t & 3) << 5;
    u16 tmp[32];
    #pragma unroll
    for (int j = 0; j < 32; ++j) tmp[j] = tile[(rW + j) * 129 + cW];
    u16* dp = dst + (size_t)(tc * 128 + cW) * R + tr * 128 + rW;
    *(uint4*)(dp)      = *(const uint4*)(tmp);
    *(uint4*)(dp + 8)  = *(const uint4*)(tmp + 8);
    *(uint4*)(dp + 16) = *(const uint4*)(tmp + 16);
    *(uint4*)(dp + 24) = *(const uint4*)(tmp + 24);
}

// ---------------------------------------------------------------------------
// Map routed block index -> (expert, 256-row m-tile, col-block, act base,
// padded-128 row count). 4 col-blocks per m-tile in both GEMMs.
// ---------------------------------------------------------------------------
__device__ __forceinline__ int derive256(int gi, const int* cnt,
        int& e, int& mt, int& sub, int& abase, int& rowsE)
{
    int off = 0, b = 0;
    #pragma unroll
    for (int ee = 0; ee < E_NUM; ++ee) {
        int cc = cnt[ee * CSTR];
        int rE = ((cc + 127) >> 7) << 7;
        int mts = (rE + 255) >> 8;
        int span = mts << 2;
        if (gi < off + span) {
            int local = gi - off;
            e = ee; mt = local >> 2; sub = local & 3; abase = b; rowsE = rE;
            return 1;
        }
        off += span; b += rE;
    }
    return 0;
}

// ---------------------------------------------------------------------------
// k_prep: router (+ xb emission) and gate/up + shared gate/up transposes.
// ---------------------------------------------------------------------------
__global__ __launch_bounds__(256, 4)
void k_prep(const float* x, const float* rw,
            const float* wg, const float* wu, const float* sg, const float* su,
            u16* wgt, u16* wut, u16* sgt, u16* sut,
            u16* xb, float* topkw, int* elist, int* cnt)
{
    __shared__ u16 tile[64 * 65];
    int bi = blockIdx.x;
    if (bi >= P_RT) {
        if (bi < P_WU)      tr64(wg, wgt, 1024, 512,  bi - P_RT, tile);
        else if (bi < P_SG) tr64(wu, wut, 1024, 512,  bi - P_WU, tile);
        else if (bi < P_SU) tr64(sg, sgt, 1024, 1024, bi - P_SG, tile);
        else                tr64(su, sut, 1024, 1024, bi - P_SU, tile);
        return;
    }
    int lane = threadIdx.x & 63;
    int wv = threadIdx.x >> 6;
    int t = bi * 4 + wv;
    const float* xr = x + (size_t)t * H_DIM;
    float xv[16];
    #pragma unroll
    for (int j = 0; j < 16; ++j) xv[j] = xr[j * 64 + lane];
    u16* xrow = xb + (size_t)t * H_DIM;
    #pragma unroll
    for (int j = 0; j < 16; ++j) xrow[j * 64 + lane] = f2bf(xv[j]);
    float sc[E_NUM];
    #pragma unroll
    for (int e = 0; e < E_NUM; ++e) sc[e] = 0.f;
    #pragma unroll
    for (int e = 0; e < E_NUM; ++e) {
        const float* rr = rw + e * H_DIM;
        #pragma unroll
        for (int j = 0; j < 16; ++j) sc[e] += xv[j] * rr[j * 64 + lane];
    }
    #pragma unroll
    for (int off = 32; off > 0; off >>= 1) {
        float tmp[E_NUM];
        #pragma unroll
        for (int e = 0; e < E_NUM; ++e) tmp[e] = __shfl_xor(sc[e], off, 64);
        #pragma unroll
        for (int e = 0; e < E_NUM; ++e) sc[e] += tmp[e];
    }
    if (lane == 0) {
        float b1 = -1e30f, b2 = -1e30f; int i1 = 0, i2 = 0;
        #pragma unroll
        for (int e = 0; e < E_NUM; ++e) {
            if (sc[e] > b1) { b2 = b1; i2 = i1; b1 = sc[e]; i1 = e; }
            else if (sc[e] > b2) { b2 = sc[e]; i2 = e; }
        }
        float w1 = 1.f / (1.f + __expf(b2 - b1));
        float w2 = 1.f - w1;
        topkw[t * 2]     = w1;
        topkw[t * 2 + 1] = w2;
        int p1 = atomicAdd(&cnt[i1 * CSTR], 1); elist[i1 * T_TOK + p1] = (t << 1);
        int p2 = atomicAdd(&cnt[i2 * CSTR], 1); elist[i2 * T_TOK + p2] = (t << 1) | 1;
    }
}

// ---- shared 8-phase core pieces -------------------------------------------
#define STG(part, buf, tt) { \
    u16* d_ = sm + (buf) * 32768 + (part) * 8192 + w * 512; \
    gld16(pst[part][0] + (tt) * 64, d_); \
    gld16(pst[part][1] + (tt) * 64, d_ + 4096); }

#define RD(o) (*(const short8*)(sm + bsel * 32768 + (o)))

#define MM16(ACC, AA, J0) \
    _Pragma("unroll") \
    for (int mi = 0; mi < 4; ++mi) \
        _Pragma("unroll") \
        for (int j = 0; j < 2; ++j) \
            _Pragma("unroll") \
            for (int kh = 0; kh < 2; ++kh) \
                ACC[mi][j] = __builtin_amdgcn_mfma_f32_16x16x32_bf16( \
                    AA[mi][kh], bq[(J0) + j][kh], ACC[mi][j], 0, 0, 0);

// ---------------------------------------------------------------------------
// k_gateup: 256x(128g+128u) blocks, K=1024, 8-phase pipeline.
// ---------------------------------------------------------------------------
__global__ __launch_bounds__(512, 2)
void k_gateup(const u16* xb, const u16* wgt, const u16* wut,
              const u16* sgt, const u16* sut,
              const float* wd, const float* sd, u16* wdt, u16* sdt,
              const int* elist, const int* cnt,
              u16* act, u16* sact)
{
    __shared__ u16 sm[65536];   // 128 KB
    int bi = blockIdx.x;
    if (bi >= G_GEMM) {
        int tb = bi - G_GEMM;
        if (tb < 512) tr128(wd, wdt, 512, 1024, tb, sm);
        else          tr128(sd, sdt, 1024, 1024, tb - 512, sm);
        return;
    }
    int kind, e = 0, mt, cb, abase = 0, rowsE = 0;
    if (bi < 128) { kind = 1; mt = bi >> 3; cb = bi & 7; }
    else { kind = 0; if (!derive256(bi - 128, cnt, e, mt, cb, abase, rowsE)) return; }

    int tid = threadIdx.x, lane = tid & 63, w = tid >> 6;
    int wr = w >> 2, wc = w & 3;
    int quad = lane >> 4, l15 = lane & 15;
    int l8r = lane >> 3, l8c = lane & 7;
    int sg = (l8c ^ l8r) * 8;             // pre-swizzled source slot (bytes/2)
    int c = kind ? 0 : cnt[e * CSTR];

    const u16* gb = kind ? sgt : (wgt + (size_t)e * I_DIM * H_DIM);
    const u16* ub = kind ? sut : (wut + (size_t)e * I_DIM * H_DIM);

    const u16* pst[4][2];
    #pragma unroll
    for (int part = 0; part < 2; ++part)
        #pragma unroll
        for (int l = 0; l < 2; ++l) {
            int R = part * 128 + l * 64 + w * 8 + l8r;
            int tok;
            if (kind) tok = mt * 256 + R;
            else { int p = mt * 256 + R; int pc = p < c ? p : c - 1;
                   tok = elist[e * T_TOK + pc] >> 1; }
            pst[part][l] = xb + (size_t)tok * H_DIM + sg;
        }
    #pragma unroll
    for (int l = 0; l < 2; ++l) {
        int n = cb * 128 + l * 64 + w * 8 + l8r;
        pst[2][l] = gb + (size_t)n * H_DIM + sg;
        pst[3][l] = ub + (size_t)n * H_DIM + sg;
    }

    int slot0 = (quad ^ (l15 & 7)) * 8;
    int slot1 = ((4 + quad) ^ (l15 & 7)) * 8;
    int baseA0 = wr * 8192 + l15 * 64 + slot0;
    int baseA1 = wr * 8192 + l15 * 64 + slot1;
    int baseB0 = 16384 + wc * 2048 + l15 * 64 + slot0;
    int baseB1 = 16384 + wc * 2048 + l15 * 64 + slot1;

    floatx4 accL[8][2], accU[8][2];
    #pragma unroll
    for (int i = 0; i < 8; ++i)
        #pragma unroll
        for (int j = 0; j < 2; ++j)
            #pragma unroll
            for (int r = 0; r < 4; ++r) { accL[i][j][r] = 0.f; accU[i][j][r] = 0.f; }
    short8 a0[4][2], a1[4][2], bq[4][2];

    // prologue: half-tiles h=0..4 (Ah0,Ah1,Bh0,Bh1 of t0; Ah0 of t1)
    STG(0, 0, 0); STG(1, 0, 0); STG(2, 0, 0); STG(3, 0, 0); STG(0, 1, 1);
    VM4; BAR;

    const int nt = H_DIM / 64;   // 16
    for (int t = 0; t < nt; ++t) {
        int bsel = t & 1, bnx = bsel ^ 1;
        bool last = (t == nt - 1), pen = (t == nt - 2);
        // phase 0: A-mh0 + B-low -> accL[0..3]
        if (!last) STG(1, bnx, t + 1);
        #pragma unroll
        for (int mi = 0; mi < 4; ++mi) {
            a0[mi][0] = RD(baseA0 + mi * 1024);
            a0[mi][1] = RD(baseA1 + mi * 1024);
        }
        #pragma unroll
        for (int j = 0; j < 2; ++j) {
            bq[j][0] = RD(baseB0 + j * 1024);
            bq[j][1] = RD(baseB1 + j * 1024);
        }
        if (last) { VM0; } else { VM4; }
        BAR; LGKM0; SCHB;
        __builtin_amdgcn_s_setprio(1);
        MM16(accL, a0, 0);
        __builtin_amdgcn_s_setprio(0);
        SCHB; BAR;
        // phase 1: B-high -> accU[0..3]
        if (!last) STG(2, bnx, t + 1);
        #pragma unroll
        for (int j = 0; j < 2; ++j) {
            bq[2 + j][0] = RD(baseB0 + 8192 + j * 1024);
            bq[2 + j][1] = RD(baseB1 + 8192 + j * 1024);
        }
        if (last) { VM0; } else { VM6; }
        BAR; LGKM0; SCHB;
        __builtin_amdgcn_s_setprio(1);
        MM16(accU, a0, 2);
        __builtin_amdgcn_s_setprio(0);
        SCHB; BAR;
        // phase 2: A-mh1 -> accL[4..7]
        if (!last) STG(3, bnx, t + 1);
        #pragma unroll
        for (int mi = 0; mi < 4; ++mi) {
            a1[mi][0] = RD(baseA0 + 4096 + mi * 1024);
            a1[mi][1] = RD(baseA1 + 4096 + mi * 1024);
        }
        if (last) { VM0; } else { VM6; }
        BAR; LGKM0; SCHB;
        __builtin_amdgcn_s_setprio(1);
        MM16((&accL[4]), a1, 0);
        __builtin_amdgcn_s_setprio(0);
        SCHB; BAR;
        // phase 3: -> accU[4..7]
        if (t + 2 < nt) STG(0, bsel, t + 2);
        if (last) { VM0; } else if (pen) { VM2; } else { VM4; }
        BAR; LGKM0; SCHB;
        __builtin_amdgcn_s_setprio(1);
        MM16((&accU[4]), a1, 2);
        __builtin_amdgcn_s_setprio(0);
        SCHB; BAR;
    }

    u16* ob; int ostride;
    if (kind) { ob = sact + (size_t)(mt * 256) * IS_DIM; ostride = IS_DIM; }
    else      { ob = act + (size_t)(abase + mt * 256) * I_DIM; ostride = I_DIM; }
    #pragma unroll
    for (int mi = 0; mi < 8; ++mi)
        #pragma unroll
        for (int j = 0; j < 2; ++j)
            #pragma unroll
            for (int r = 0; r < 4; ++r) {
                int row = wr * 128 + mi * 16 + quad * 4 + r;
                int col = cb * 128 + wc * 32 + j * 16 + l15;
                float gg = accL[mi][j][r], uu = accU[mi][j][r];
                float aa = gg / (1.f + __expf(-gg)) * uu;
                if (kind || (mt * 256 + row < rowsE))
                    ob[(size_t)row * ostride + col] = f2bf(aa);
            }
}

// ---------------------------------------------------------------------------
// k_down: 256x256 blocks, 8-phase pipeline. Routed K=512 -> y0/y1 scatter;
// shared K=1024 -> f32 out.
// ---------------------------------------------------------------------------
__global__ __launch_bounds__(512, 2)
void k_down(const u16* act, const u16* sact, const u16* wdt, const u16* sdt,
            const int* elist, const int* cnt, const float* topkw,
            u16* y0, u16* y1, float* out)
{
    __shared__ u16 sm[65536];
    int bi = blockIdx.x;
    int kind, e = 0, mt, nb, abase = 0, rowsE = 0;
    if (bi < 64) { kind = 1; mt = bi >> 2; nb = bi & 3; }
    else { kind = 0; if (!derive256(bi - 64, cnt, e, mt, nb, abase, rowsE)) return; }

    int tid = threadIdx.x, lane = tid & 63, w = tid >> 6;
    int wr = w >> 2, wc = w & 3;
    int quad = lane >> 4, l15 = lane & 15;
    int l8r = lane >> 3, l8c = lane & 7;
    int sg = (l8c ^ l8r) * 8;
    int c = kind ? 0 : cnt[e * CSTR];

    int K = kind ? IS_DIM : I_DIM;
    const u16* ab = kind ? (sact + (size_t)(mt * 256) * IS_DIM)
                         : (act + (size_t)(abase + mt * 256) * I_DIM);
    const u16* bb = kind ? sdt : (wdt + (size_t)e * H_DIM * I_DIM);

    const u16* pst[4][2];
    #pragma unroll
    for (int part = 0; part < 2; ++part)
        #pragma unroll
        for (int l = 0; l < 2; ++l) {
            int R = part * 128 + l * 64 + w * 8 + l8r;
            pst[part][l] = ab + (size_t)R * K + sg;
        }
    #pragma unroll
    for (int l = 0; l < 2; ++l) {
        int n = nb * 256 + l * 64 + w * 8 + l8r;
        pst[2][l] = bb + (size_t)n * K + sg;
        pst[3][l] = bb + (size_t)(n + 128) * K + sg;
    }

    int slot0 = (quad ^ (l15 & 7)) * 8;
    int slot1 = ((4 + quad) ^ (l15 & 7)) * 8;
    int baseA0 = wr * 8192 + l15 * 64 + slot0;
    int baseA1 = wr * 8192 + l15 * 64 + slot1;
    int baseB0 = 16384 + wc * 2048 + l15 * 64 + slot0;
    int baseB1 = 16384 + wc * 2048 + l15 * 64 + slot1;

    floatx4 accL[8][2], accU[8][2];
    #pragma unroll
    for (int i = 0; i < 8; ++i)
        #pragma unroll
        for (int j = 0; j < 2; ++j)
            #pragma unroll
            for (int r = 0; r < 4; ++r) { accL[i][j][r] = 0.f; accU[i][j][r] = 0.f; }
    short8 a0[4][2], a1[4][2], bq[4][2];

    STG(0, 0, 0); STG(1, 0, 0); STG(2, 0, 0); STG(3, 0, 0); STG(0, 1, 1);
    VM4; BAR;

    const int nt = K >> 6;       // 8 or 16
    for (int t = 0; t < nt; ++t) {
        int bsel = t & 1, bnx = bsel ^ 1;
        bool last = (t == nt - 1), pen = (t == nt - 2);
        if (!last) STG(1, bnx, t + 1);
        #pragma unroll
        for (int mi = 0; mi < 4; ++mi) {
            a0[mi][0] = RD(baseA0 + mi * 1024);
            a0[mi][1] = RD(baseA1 + mi * 1024);
        }
        #pragma unroll
        for (int j = 0; j < 2; ++j) {
            bq[j][0] = RD(baseB0 + j * 1024);
            bq[j][1] = RD(baseB1 + j * 1024);
        }
        if (last) { VM0; } else { VM4; }
        BAR; LGKM0; SCHB;
        __builtin_amdgcn_s_setprio(1);
        MM16(accL, a0, 0);
        __builtin_amdgcn_s_setprio(0);
        SCHB; BAR;
        if (!last) STG(2, bnx, t + 1);
        #pragma unroll
        for (int j = 0; j < 2; ++j) {
            bq[2 + j][0] = RD(baseB0 + 8192 + j * 1024);
            bq[2 + j][1] = RD(baseB1 + 8192 + j * 1024);
        }
        if (last) { VM0; } else { VM6; }
        BAR; LGKM0; SCHB;
        __builtin_amdgcn_s_setprio(1);
        MM16(accU, a0, 2);
        __builtin_amdgcn_s_setprio(0);
        SCHB; BAR;
        if (!last) STG(3, bnx, t + 1);
        #pragma unroll
        for (int mi = 0; mi < 4; ++mi) {
            a1[mi][0] = RD(baseA0 + 4096 + mi * 1024);
            a1[mi][1] = RD(baseA1 + 4096 + mi * 1024);
        }
        if (last) { VM0; } else { VM6; }
        BAR; LGKM0; SCHB;
        __builtin_amdgcn_s_setprio(1);
        MM16((&accL[4]), a1, 0);
        __builtin_amdgcn_s_setprio(0);
        SCHB; BAR;
        if (t + 2 < nt) STG(0, bsel, t + 2);
        if (last) { VM0; } else if (pen) { VM2; } else { VM4; }
        BAR; LGKM0; SCHB;
        __builtin_amdgcn_s_setprio(1);
        MM16((&accU[4]), a1, 2);
        __builtin_amdgcn_s_setprio(0);
        SCHB; BAR;
    }

    if (kind) {
        #pragma unroll
        for (int mi = 0; mi < 8; ++mi)
            #pragma unroll
            for (int r = 0; r < 4; ++r) {
                int row = mt * 256 + wr * 128 + mi * 16 + quad * 4 + r;
                #pragma unroll
                for (int j = 0; j < 2; ++j) {
                    out[(size_t)row * H_DIM + nb * 256 + wc * 32 + j * 16 + l15] = accL[mi][j][r];
                    out[(size_t)row * H_DIM + nb * 256 + 128 + wc * 32 + j * 16 + l15] = accU[mi][j][r];
                }
            }
    } else {
        #pragma unroll
        for (int mi = 0; mi < 8; ++mi)
            #pragma unroll
            for (int r = 0; r < 4; ++r) {
                int p = mt * 256 + wr * 128 + mi * 16 + quad * 4 + r;
                if (p < c) {
                    int ent = elist[e * T_TOK + p];
                    int tok = ent >> 1, sl = ent & 1;
                    float wt = topkw[tok * 2 + sl];
                    u16* yb = sl ? y1 : y0;
                    #pragma unroll
                    for (int j = 0; j < 2; ++j) {
                        yb[(size_t)tok * H_DIM + nb * 256 + wc * 32 + j * 16 + l15] =
                            f2bf(wt * accL[mi][j][r]);
                        yb[(size_t)tok * H_DIM + nb * 256 + 128 + wc * 32 + j * 16 + l15] =
                            f2bf(wt * accU[mi][j][r]);
                    }
                }
            }
    }
}

// Final combine: out += y0 + y1 (out already holds shared-expert result).
__global__ __launch_bounds__(256)
void k_final(float* out, const u16* y0, const u16* y1)
{
    int i = blockIdx.x * 256 + threadIdx.x;
    float4 o = ((const float4*)out)[i];
    uint2 a = ((const uint2*)y0)[i];
    uint2 b = ((const uint2*)y1)[i];
    const u16* pa = (const u16*)&a;
    const u16* pb = (const u16*)&b;
    o.x += bf2f(pa[0]) + bf2f(pb[0]);
    o.y += bf2f(pa[1]) + bf2f(pb[1]);
    o.z += bf2f(pa[2]) + bf2f(pb[2]);
    o.w += bf2f(pa[3]) + bf2f(pb[3]);
    ((float4*)out)[i] = o;
}

// ---------------------------------------------------------------------------
extern "C" void kernel_launch(void* const* d_in, const int* in_sizes, int n_in,
                              void* d_out, int out_size, void* d_ws, size_t ws_size,
                              hipStream_t stream)
{
    const float* x  = (const float*)d_in[0];
    const float* rw = (const float*)d_in[1];
    const float* wg = (const float*)d_in[2];
    const float* wu = (const float*)d_in[3];
    const float* wd = (const float*)d_in[4];
    const float* sg = (const float*)d_in[5];
    const float* su = (const float*)d_in[6];
    const float* sd = (const float*)d_in[7];
    float* out = (float*)d_out;

    char* ws = (char*)d_ws;
    const size_t MB = 1024ull * 1024ull;
    u16* wgt  = (u16*)(ws);            // [E][I][H] bf16  16 MB
    u16* wut  = (u16*)(ws + 16 * MB);  // 16 MB
    u16* wdt  = (u16*)(ws + 32 * MB);  // [E][H][I]       16 MB
    u16* sgt  = (u16*)(ws + 48 * MB);  //  2 MB
    u16* sut  = (u16*)(ws + 50 * MB);  //  2 MB
    u16* sdt  = (u16*)(ws + 52 * MB);  //  2 MB
    u16* xb   = (u16*)(ws + 54 * MB);  //  8 MB
    u16* act  = (u16*)(ws + 62 * MB);  // 12 MB (128-padded rows, 256-tile reads)
    u16* sact = (u16*)(ws + 74 * MB);  //  8 MB
    u16* y0   = (u16*)(ws + 82 * MB);  //  8 MB
    u16* y1   = (u16*)(ws + 90 * MB);  //  8 MB
    float* topkw  = (float*)(ws + 98 * MB);            // 32 KB
    int* elist    = (int*)(ws + 98 * MB + 64 * 1024);  // 256 KB
    int* cnt      = (int*)(ws + 98 * MB + 512 * 1024); // 2 KB

    hipMemsetAsync(cnt, 0, E_NUM * CSTR * sizeof(int), stream);
    k_prep<<<P_END, 256, 0, stream>>>(x, rw, wg, wu, sg, su,
                                      wgt, wut, sgt, sut,
                                      xb, topkw, elist, cnt);
    k_gateup<<<G_END, 512, 0, stream>>>(xb, wgt, wut, sgt, sut,
                                        wd, sd, wdt, sdt,
                                        elist, cnt, act, sact);
    k_down<<<D_GRID, 512, 0, stream>>>(act, sact, wdt, sdt,
                                       elist, cnt, topkw, y0, y1, out);
    k_final<<<T_TOK * H_DIM / 4 / 256, 256, 0, stream>>>(out, y0, y1);
}

// Round 6
// 271.106 us; speedup vs baseline: 1.2146x; 1.0307x over previous
//
#include <hip/hip_runtime.h>
#include <math.h>

// SigmaMoE R13 (consolidation): T=4096, H=1024, I=512, E=16, top-2, IS=1024.
// R5 post-mortem: 256-tile 8-phase starved the grid (352 blocks @ 1/CU =
// 1.375 rounds) and 128KB LDS poisoned the transpose tail. Revert to the
// best-known-good 2-phase 32KB cores (R0/R1) everywhere; single deliberate
// change: __launch_bounds__(256,3) on both GEMMs (was (256,2)) — the m97
// reference structure runs ~900TF at 3 blocks/CU vs our ~610TF at 2.
//  - k_prep: router (+xb) + wg/wu/sg/su tr64 transposes.
//  - k_gateup: 128x(64g+64u), BK=64, 2-phase, 32KB; wd/sd tr64 at grid TAIL.
//  - k_down: 128x128, BK=64, 2-phase, 32KB; routed->y0/y1, shared->f32 out.
//  - k_final: out += y0 + y1.
#define H_DIM 1024
#define I_DIM 512
#define E_NUM 16
#define T_TOK 4096
#define IS_DIM 1024
#define CSTR 32       // cnt stride in ints (128B = own cache line per expert)

// k_prep block ranges
#define P_RT   1024               // router blocks (4 tokens each)
#define P_WU   (P_RT + 2048)      // wg transpose
#define P_SG   (P_WU + 2048)      // wu transpose
#define P_SU   (P_SG + 256)       // sg transpose
#define P_END  (P_SU + 256)       // su transpose

// k_gateup: GEMM blocks FIRST, transpose blocks at tail.
#define G_GEMM 1152               // 512 shared + <=640 routed
#define G_TR   2304               // wd (2048) + sd (256)
#define G_END  (G_GEMM + G_TR)

#define D_GRID 896                // 256 shared + <=640 routed

typedef unsigned short u16;
typedef __attribute__((ext_vector_type(8))) short short8;   // 8 x bf16 (16B)
typedef __attribute__((ext_vector_type(4))) float floatx4;  // 16x16 acc

__device__ __forceinline__ float bf2f(u16 u) {
    union { unsigned int u; float f; } c; c.u = ((unsigned int)u) << 16; return c.f;
}
__device__ __forceinline__ u16 f2bf(float f) {
    union { float f; unsigned int u; } c; c.f = f;
    unsigned int r = (c.u + 0x7fffu + ((c.u >> 16) & 1u)) >> 16;
    return (u16)r;
}
// async global->LDS, 16B/lane; LDS dest = wave-uniform base + lane*16.
__device__ __forceinline__ void gld16(const u16* g, u16* l) {
    __builtin_amdgcn_global_load_lds(
        (const __attribute__((address_space(1))) unsigned int*)g,
        (__attribute__((address_space(3))) unsigned int*)l, 16, 0, 0);
}

// ---------------------------------------------------------------------------
// 64x64 convert+transpose tile: f32 K-major -> bf16 N-major. tile = 64*65 u16.
// ---------------------------------------------------------------------------
__device__ __forceinline__ void tr64(const float* src, u16* dst, int R, int C,
                                     int local, u16* tile)
{
    int tpm = (R >> 6) * (C >> 6);
    int mat = local / tpm;
    int tl_ = local - mat * tpm;
    int tcn = C >> 6;
    int tr = tl_ / tcn, tc = tl_ - tr * tcn;
    src += (size_t)mat * R * C;
    dst += (size_t)mat * R * C;
    int t = threadIdx.x;
    int r0 = t >> 2, c0 = (t & 3) << 4;
    const float* sp = src + (size_t)(tr * 64 + r0) * C + tc * 64 + c0;
    #pragma unroll
    for (int j = 0; j < 16; j += 4) {
        float4 v = *(const float4*)(sp + j);
        tile[r0 * 65 + c0 + j + 0] = f2bf(v.x);
        tile[r0 * 65 + c0 + j + 1] = f2bf(v.y);
        tile[r0 * 65 + c0 + j + 2] = f2bf(v.z);
        tile[r0 * 65 + c0 + j + 3] = f2bf(v.w);
    }
    __syncthreads();
    int cW = t >> 2, rW = (t & 3) << 4;
    u16 tmp[16];
    #pragma unroll
    for (int j = 0; j < 16; ++j) tmp[j] = tile[(rW + j) * 65 + cW];
    u16* dp = dst + (size_t)(tc * 64 + cW) * R + tr * 64 + rW;
    *(uint4*)(dp)     = *(const uint4*)(tmp);
    *(uint4*)(dp + 8) = *(const uint4*)(tmp + 8);
}

// ---------------------------------------------------------------------------
// Map a routed block index to (expert, m-tile, sub-tile, act row base).
// ---------------------------------------------------------------------------
__device__ __forceinline__ int derive_routed(int gi, const int* cnt,
                                             int& e, int& mt, int& sub, int& abase)
{
    int off = 0, b = 0;
    #pragma unroll
    for (int ee = 0; ee < E_NUM; ++ee) {
        int mts = (cnt[ee * CSTR] + 127) >> 7;
        int span = mts << 3;
        if (gi < off + span) {
            int local = gi - off;
            e = ee; mt = local >> 3; sub = local & 7; abase = b;
            return 1;
        }
        off += span; b += mts << 7;
    }
    return 0;
}

// ---------------------------------------------------------------------------
// k_prep: router (+ xb emission) and gate/up + shared gate/up transposes.
// ---------------------------------------------------------------------------
__global__ __launch_bounds__(256, 4)
void k_prep(const float* x, const float* rw,
            const float* wg, const float* wu, const float* sg, const float* su,
            u16* wgt, u16* wut, u16* sgt, u16* sut,
            u16* xb, float* topkw, int* elist, int* cnt)
{
    __shared__ u16 tile[64 * 65];
    int bi = blockIdx.x;
    if (bi >= P_RT) {
        if (bi < P_WU)      tr64(wg, wgt, 1024, 512,  bi - P_RT, tile);
        else if (bi < P_SG) tr64(wu, wut, 1024, 512,  bi - P_WU, tile);
        else if (bi < P_SU) tr64(sg, sgt, 1024, 1024, bi - P_SG, tile);
        else                tr64(su, sut, 1024, 1024, bi - P_SU, tile);
        return;
    }
    // ---- router + x->bf16 (4 tokens per block, 1 wave each) ----
    int lane = threadIdx.x & 63;
    int wv = threadIdx.x >> 6;
    int t = bi * 4 + wv;
    const float* xr = x + (size_t)t * H_DIM;
    float xv[16];
    #pragma unroll
    for (int j = 0; j < 16; ++j) xv[j] = xr[j * 64 + lane];
    u16* xrow = xb + (size_t)t * H_DIM;
    #pragma unroll
    for (int j = 0; j < 16; ++j) xrow[j * 64 + lane] = f2bf(xv[j]);
    float sc[E_NUM];
    #pragma unroll
    for (int e = 0; e < E_NUM; ++e) sc[e] = 0.f;
    #pragma unroll
    for (int e = 0; e < E_NUM; ++e) {
        const float* rr = rw + e * H_DIM;
        #pragma unroll
        for (int j = 0; j < 16; ++j) sc[e] += xv[j] * rr[j * 64 + lane];
    }
    #pragma unroll
    for (int off = 32; off > 0; off >>= 1) {
        float tmp[E_NUM];
        #pragma unroll
        for (int e = 0; e < E_NUM; ++e) tmp[e] = __shfl_xor(sc[e], off, 64);
        #pragma unroll
        for (int e = 0; e < E_NUM; ++e) sc[e] += tmp[e];
    }
    if (lane == 0) {
        float b1 = -1e30f, b2 = -1e30f; int i1 = 0, i2 = 0;
        #pragma unroll
        for (int e = 0; e < E_NUM; ++e) {
            if (sc[e] > b1) { b2 = b1; i2 = i1; b1 = sc[e]; i1 = e; }
            else if (sc[e] > b2) { b2 = sc[e]; i2 = e; }
        }
        float w1 = 1.f / (1.f + __expf(b2 - b1));
        float w2 = 1.f - w1;
        topkw[t * 2]     = w1;
        topkw[t * 2 + 1] = w2;
        int p1 = atomicAdd(&cnt[i1 * CSTR], 1); elist[i1 * T_TOK + p1] = (t << 1);
        int p2 = atomicAdd(&cnt[i2 * CSTR], 1); elist[i2 * T_TOK + p2] = (t << 1) | 1;
    }
}

// ---------------------------------------------------------------------------
// Fused gate/up GEMM (routed + shared). Block = 128 rows x (64 g + 64 u),
// BK=64 (2 k-chunks per barrier), 32 MFMA per barrier-pair, 32KB LDS.
// wd/sd transposes at grid TAIL. (256,3): 3 blocks/CU (was 2).
// ---------------------------------------------------------------------------
__global__ __launch_bounds__(256, 3)
void k_gateup(const u16* xb, const u16* wgt, const u16* wut,
              const u16* sgt, const u16* sut,
              const float* wd, const float* sd, u16* wdt, u16* sdt,
              const int* elist, const int* cnt,
              u16* act, u16* sact)
{
    __shared__ u16 smem[128 * 64 + 64 * 64 + 64 * 64];   // 32 KB
    int bi = blockIdx.x;
    if (bi >= G_GEMM) {
        int tb = bi - G_GEMM;
        if (tb < 2048) tr64(wd, wdt, 512, 1024, tb, smem);
        else           tr64(sd, sdt, 1024, 1024, tb - 2048, smem);
        return;
    }
    int kind, e = 0, mt, cb, abase = 0;
    if (bi < 512) { kind = 1; mt = bi >> 4; cb = bi & 15; }
    else {
        kind = 0;
        if (!derive_routed(bi - 512, cnt, e, mt, cb, abase)) return;
    }

    u16* lA = smem;              // [2 chunks][8 calls][512] = 128x64
    u16* lG = smem + 8192;       // [2][4][512] = 64x64
    u16* lU = smem + 12288;
    int tid = threadIdx.x, lane = tid & 63, w = tid >> 6;
    int srow = lane >> 2, scp = lane & 3;

    const u16* gb = kind ? sgt : (wgt + (size_t)e * I_DIM * H_DIM);
    const u16* ub = kind ? sut : (wut + (size_t)e * I_DIM * H_DIM);
    int c = cnt[e * CSTR];

    const u16 *gA[2], *gG, *gU;
    u16 *dA[2], *dG, *dU;
    #pragma unroll
    for (int jj = 0; jj < 2; ++jj) {
        int call = w * 2 + jj;
        int row = call * 16 + srow;               // 0..127
        int gc = scp ^ ((row >> 1) & 3);
        int tok;
        if (kind) tok = mt * 128 + row;
        else {
            int p = mt * 128 + row;
            int pc = p < c ? p : c - 1;
            tok = elist[e * T_TOK + pc] >> 1;
        }
        gA[jj] = xb + (size_t)tok * H_DIM + gc * 8;
        dA[jj] = lA + call * 512;
    }
    {
        int row = w * 16 + srow;                  // 0..63
        int gc = scp ^ ((row >> 1) & 3);
        gG = gb + (size_t)(cb * 64 + row) * H_DIM + gc * 8;
        gU = ub + (size_t)(cb * 64 + row) * H_DIM + gc * 8;
        dG = lG + w * 512;
        dU = lU + w * 512;
    }

    int wr = w >> 1, wc = w & 1;
    int quad = lane >> 4, l15 = lane & 15;
    const u16 *fA[4], *fG[2], *fU[2];
    #pragma unroll
    for (int i = 0; i < 4; ++i) {
        int r = wr * 64 + i * 16 + l15;
        fA[i] = lA + r * 32 + (quad ^ ((r >> 1) & 3)) * 8;
    }
    #pragma unroll
    for (int j = 0; j < 2; ++j) {
        int n = wc * 32 + j * 16 + l15;
        fG[j] = lG + n * 32 + (quad ^ ((n >> 1) & 3)) * 8;
        fU[j] = lU + n * 32 + (quad ^ ((n >> 1) & 3)) * 8;
    }

    floatx4 accg[4][2], accu[4][2];
    #pragma unroll
    for (int i = 0; i < 4; ++i)
        #pragma unroll
        for (int j = 0; j < 2; ++j)
            #pragma unroll
            for (int r = 0; r < 4; ++r) { accg[i][j][r] = 0.f; accu[i][j][r] = 0.f; }

    for (int s = 0; s < H_DIM / 64; ++s) {
        #pragma unroll
        for (int q = 0; q < 2; ++q) {
            gld16(gA[0] + q * 32, dA[0] + q * 4096);
            gld16(gA[1] + q * 32, dA[1] + q * 4096);
            gld16(gG + q * 32, dG + q * 2048);
            gld16(gU + q * 32, dU + q * 2048);
        }
        gA[0] += 64; gA[1] += 64; gG += 64; gU += 64;
        __syncthreads();
        #pragma unroll
        for (int q = 0; q < 2; ++q) {
            short8 a[4], g[2], u[2];
            #pragma unroll
            for (int i = 0; i < 4; ++i) a[i] = *(const short8*)(fA[i] + q * 4096);
            #pragma unroll
            for (int j = 0; j < 2; ++j) {
                g[j] = *(const short8*)(fG[j] + q * 2048);
                u[j] = *(const short8*)(fU[j] + q * 2048);
            }
            #pragma unroll
            for (int i = 0; i < 4; ++i)
                #pragma unroll
                for (int j = 0; j < 2; ++j) {
                    accg[i][j] = __builtin_amdgcn_mfma_f32_16x16x32_bf16(a[i], g[j], accg[i][j], 0, 0, 0);
                    accu[i][j] = __builtin_amdgcn_mfma_f32_16x16x32_bf16(a[i], u[j], accu[i][j], 0, 0, 0);
                }
        }
        __syncthreads();
    }

    u16* obase = kind ? (sact + (size_t)(mt * 128) * IS_DIM)
                      : (act + (size_t)(abase + mt * 128) * I_DIM);
    int old = kind ? IS_DIM : I_DIM;
    #pragma unroll
    for (int i = 0; i < 4; ++i)
        #pragma unroll
        for (int j = 0; j < 2; ++j)
            #pragma unroll
            for (int r = 0; r < 4; ++r) {
                int row = wr * 64 + i * 16 + quad * 4 + r;
                int col = cb * 64 + wc * 32 + j * 16 + l15;
                float gg = accg[i][j][r], uu = accu[i][j][r];
                float aa = gg / (1.f + __expf(-gg)) * uu;   // silu(g)*u
                obase[(size_t)row * old + col] = f2bf(aa);
            }
}

// ---------------------------------------------------------------------------
// Fused down GEMM. Block = 128 rows x 128 cols, BK=64, 2-phase, 32KB LDS.
// Routed K=512 -> y0/y1 scatter; shared K=1024 -> f32 out.
// ---------------------------------------------------------------------------
__global__ __launch_bounds__(256, 3)
void k_down(const u16* act, const u16* sact, const u16* wdt, const u16* sdt,
            const int* elist, const int* cnt, const float* topkw,
            u16* y0, u16* y1, float* out)
{
    int bi = blockIdx.x;
    int kind, e = 0, mt, nb, abase = 0;
    if (bi < 256) { kind = 1; mt = bi >> 3; nb = bi & 7; }     // 32 mts x 8 nbs
    else {
        kind = 0;
        if (!derive_routed(bi - 256, cnt, e, mt, nb, abase)) return;
    }

    __shared__ u16 smem[128 * 64 * 2];     // lA + lB, 32 KB
    u16* lA = smem;              // [2][8][512] = 128 x 64
    u16* lB = smem + 8192;       // [2][8][512] = 128 x 64 (B rows = out cols)
    int tid = threadIdx.x, lane = tid & 63, w = tid >> 6;
    int srow = lane >> 2, scp = lane & 3;

    int K = kind ? IS_DIM : I_DIM;
    const u16* ab = kind ? (sact + (size_t)(mt * 128) * IS_DIM)
                         : (act + (size_t)(abase + mt * 128) * I_DIM);
    const u16* bb = kind ? (sdt + (size_t)(nb * 128) * IS_DIM)
                         : (wdt + ((size_t)e * H_DIM + nb * 128) * I_DIM);
    int c = cnt[e * CSTR];

    const u16 *gA[2], *gB[2];
    u16 *dA[2], *dB[2];
    #pragma unroll
    for (int jj = 0; jj < 2; ++jj) {
        int call = w * 2 + jj;
        int row = call * 16 + srow;               // 0..127
        int gc = scp ^ ((row >> 1) & 3);
        gA[jj] = ab + (size_t)row * K + gc * 8;
        dA[jj] = lA + call * 512;
        gB[jj] = bb + (size_t)row * K + gc * 8;
        dB[jj] = lB + call * 512;
    }

    int wr = w >> 1, wc = w & 1;
    int quad = lane >> 4, l15 = lane & 15;
    const u16 *fA[4], *fB[4];
    #pragma unroll
    for (int i = 0; i < 4; ++i) {
        int r = wr * 64 + i * 16 + l15;
        fA[i] = lA + r * 32 + (quad ^ ((r >> 1) & 3)) * 8;
    }
    #pragma unroll
    for (int j = 0; j < 4; ++j) {
        int n = wc * 64 + j * 16 + l15;
        fB[j] = lB + n * 32 + (quad ^ ((n >> 1) & 3)) * 8;
    }

    floatx4 acc[4][4];
    #pragma unroll
    for (int i = 0; i < 4; ++i)
        #pragma unroll
        for (int j = 0; j < 4; ++j)
            #pragma unroll
            for (int r = 0; r < 4; ++r) acc[i][j][r] = 0.f;

    int steps = K >> 6;
    for (int s = 0; s < steps; ++s) {
        #pragma unroll
        for (int q = 0; q < 2; ++q) {
            gld16(gA[0] + q * 32, dA[0] + q * 4096);
            gld16(gA[1] + q * 32, dA[1] + q * 4096);
            gld16(gB[0] + q * 32, dB[0] + q * 4096);
            gld16(gB[1] + q * 32, dB[1] + q * 4096);
        }
        gA[0] += 64; gA[1] += 64; gB[0] += 64; gB[1] += 64;
        __syncthreads();
        #pragma unroll
        for (int q = 0; q < 2; ++q) {
            short8 a[4], b[4];
            #pragma unroll
            for (int i = 0; i < 4; ++i) a[i] = *(const short8*)(fA[i] + q * 4096);
            #pragma unroll
            for (int j = 0; j < 4; ++j) b[j] = *(const short8*)(fB[j] + q * 4096);
            #pragma unroll
            for (int i = 0; i < 4; ++i)
                #pragma unroll
                for (int j = 0; j < 4; ++j)
                    acc[i][j] = __builtin_amdgcn_mfma_f32_16x16x32_bf16(a[i], b[j], acc[i][j], 0, 0, 0);
        }
        __syncthreads();
    }

    if (kind) {
        #pragma unroll
        for (int i = 0; i < 4; ++i)
            #pragma unroll
            for (int j = 0; j < 4; ++j)
                #pragma unroll
                for (int r = 0; r < 4; ++r) {
                    int row = mt * 128 + wr * 64 + i * 16 + quad * 4 + r;
                    int col = nb * 128 + wc * 64 + j * 16 + l15;
                    out[(size_t)row * H_DIM + col] = acc[i][j][r];
                }
    } else {
        #pragma unroll
        for (int i = 0; i < 4; ++i)
            #pragma unroll
            for (int r = 0; r < 4; ++r) {
                int row = wr * 64 + i * 16 + quad * 4 + r;
                int p = mt * 128 + row;
                if (p < c) {
                    int ent = elist[e * T_TOK + p];
                    int t = ent >> 1, sl = ent & 1;
                    float wt = topkw[t * 2 + sl];
                    u16* yb = sl ? y1 : y0;
                    #pragma unroll
                    for (int j = 0; j < 4; ++j) {
                        int col = nb * 128 + wc * 64 + j * 16 + l15;
                        yb[(size_t)t * H_DIM + col] = f2bf(wt * acc[i][j][r]);
                    }
                }
            }
    }
}

// Final combine: out += y0 + y1 (out already holds shared-expert result).
__global__ __launch_bounds__(256)
void k_final(float* out, const u16* y0, const u16* y1)
{
    int i = blockIdx.x * 256 + threadIdx.x;
    float4 o = ((const float4*)out)[i];
    uint2 a = ((const uint2*)y0)[i];
    uint2 b = ((const uint2*)y1)[i];
    const u16* pa = (const u16*)&a;
    const u16* pb = (const u16*)&b;
    o.x += bf2f(pa[0]) + bf2f(pb[0]);
    o.y += bf2f(pa[1]) + bf2f(pb[1]);
    o.z += bf2f(pa[2]) + bf2f(pb[2]);
    o.w += bf2f(pa[3]) + bf2f(pb[3]);
    ((float4*)out)[i] = o;
}

// ---------------------------------------------------------------------------
extern "C" void kernel_launch(void* const* d_in, const int* in_sizes, int n_in,
                              void* d_out, int out_size, void* d_ws, size_t ws_size,
                              hipStream_t stream)
{
    const float* x  = (const float*)d_in[0];
    const float* rw = (const float*)d_in[1];
    const float* wg = (const float*)d_in[2];
    const float* wu = (const float*)d_in[3];
    const float* wd = (const float*)d_in[4];
    const float* sg = (const float*)d_in[5];
    const float* su = (const float*)d_in[6];
    const float* sd = (const float*)d_in[7];
    float* out = (float*)d_out;

    char* ws = (char*)d_ws;
    const size_t MB = 1024ull * 1024ull;
    u16* wgt  = (u16*)(ws);            // [E][I][H] bf16  16 MB
    u16* wut  = (u16*)(ws + 16 * MB);  // [E][I][H]       16 MB
    u16* wdt  = (u16*)(ws + 32 * MB);  // [E][H][I]       16 MB
    u16* sgt  = (u16*)(ws + 48 * MB);  // [IS][H]          2 MB
    u16* sut  = (u16*)(ws + 50 * MB);  // [IS][H]          2 MB
    u16* sdt  = (u16*)(ws + 52 * MB);  // [H][IS]          2 MB
    u16* xb   = (u16*)(ws + 54 * MB);  // [T][H] bf16      8 MB
    u16* act  = (u16*)(ws + 62 * MB);  // [<=10240][I]    10 MB (128-padded rows)
    u16* sact = (u16*)(ws + 72 * MB);  // [T][IS]          8 MB
    u16* y0   = (u16*)(ws + 80 * MB);  // [T][H] slot0     8 MB
    u16* y1   = (u16*)(ws + 88 * MB);  // [T][H] slot1     8 MB
    float* topkw  = (float*)(ws + 96 * MB);            // [T][2]
    int* elist    = (int*)(ws + 96 * MB + 64 * 1024);  // [E][T]
    int* cnt      = (int*)(ws + 97 * MB);              // [E] stride CSTR

    hipMemsetAsync(cnt, 0, E_NUM * CSTR * sizeof(int), stream);
    k_prep<<<P_END, 256, 0, stream>>>(x, rw, wg, wu, sg, su,
                                      wgt, wut, sgt, sut,
                                      xb, topkw, elist, cnt);
    k_gateup<<<G_END, 256, 0, stream>>>(xb, wgt, wut, sgt, sut,
                                        wd, sd, wdt, sdt,
                                        elist, cnt, act, sact);
    k_down<<<D_GRID, 256, 0, stream>>>(act, sact, wdt, sdt,
                                       elist, cnt, topkw, y0, y1, out);
    k_final<<<T_TOK * H_DIM / 4 / 256, 256, 0, stream>>>(out, y0, y1);
}